// Round 11
// baseline (71.701 us; speedup 1.0000x reference)
//
#include <hip/hip_runtime.h>

// Problem constants (B,C,H,W,K) = (32,192,56,56,7)
#define BB 32
#define CC 192
#define HH 56
#define WW 56
#define KS 7
#define HW 3136        // 56*56
#define KK 49
#define CKK 9408       // C*K*K
#define PL 8
#define NCELL (BB * CC * KK)   // 301056
#define NBC (BB * CC)          // 6144
#define P0BLK 37               // pool blocks per sample
#define MIDBLK 24              // mid blocks per sample

typedef float f2 __attribute__((ext_vector_type(2)));

// ---------------------------------------------------------------------------
// K1: avg pool 56x56 -> 7x7 + per-block LN0 partials (no atomics).
// ---------------------------------------------------------------------------
__global__ __launch_bounds__(256) void pool_kernel(const float* __restrict__ x,
                                                   float* __restrict__ p0,
                                                   float2* __restrict__ part0) {
    __shared__ float red[8];
    int b = blockIdx.x / P0BLK;
    int t = blockIdx.x - b * P0BLK;
    int cell = t * 256 + threadIdx.x;
    float v = 0.f;
    if (cell < CKK) {
        int c = cell / KK;
        int r = cell - c * KK;
        int i = r / KS;
        int j = r - i * KS;
        const float* src = x + ((size_t)(b * CC + c)) * HW + (i * PL) * WW + j * PL;
        float s = 0.f;
#pragma unroll
        for (int a = 0; a < PL; ++a) {
            float4 v0 = *(const float4*)(src + a * WW);
            float4 v1 = *(const float4*)(src + a * WW + 4);
            s += v0.x + v0.y + v0.z + v0.w + v1.x + v1.y + v1.z + v1.w;
        }
        v = s * (1.f / 64.f);
        p0[b * CKK + cell] = v;
    }
    float sv = v, sq = v * v;
#pragma unroll
    for (int o = 32; o > 0; o >>= 1) {
        sv += __shfl_down(sv, o, 64);
        sq += __shfl_down(sq, o, 64);
    }
    if ((threadIdx.x & 63) == 0) {
        red[(threadIdx.x >> 6) * 2 + 0] = sv;
        red[(threadIdx.x >> 6) * 2 + 1] = sq;
    }
    __syncthreads();
    if (threadIdx.x == 0)
        part0[blockIdx.x] = make_float2(red[0] + red[2] + red[4] + red[6],
                                        red[1] + red[3] + red[5] + red[7]);
}

// ---------------------------------------------------------------------------
// K2: LN0-normalize + depthwise 7x7 conv on the 7x7 map, one WAVE per (b,c).
// ---------------------------------------------------------------------------
__global__ __launch_bounds__(512) void mid_kernel(
    const float* __restrict__ p0,
    const float* __restrict__ ln0w, const float* __restrict__ ln0b,
    const float* __restrict__ w0,
    const float2* __restrict__ part0,
    float* __restrict__ q1,
    float2* __restrict__ part1)
{
    __shared__ float red[16];
    int tid  = threadIdx.x;
    int lane = tid & 63;
    int bc   = blockIdx.x * 8 + (tid >> 6);
    int b = bc / CC;
    int c = bc - b * CC;

    float s0 = 0.f, ss0 = 0.f;
    if (lane < P0BLK) {
        float2 p = part0[b * P0BLK + lane];
        s0 = p.x; ss0 = p.y;
    }
#pragma unroll
    for (int o = 32; o > 0; o >>= 1) {
        s0  += __shfl_down(s0, o, 64);
        ss0 += __shfl_down(ss0, o, 64);
    }
    s0  = __shfl(s0, 0, 64);
    ss0 = __shfl(ss0, 0, 64);
    float mean = s0 * (1.f / CKK);
    float rstd = rsqrtf(ss0 * (1.f / CKK) - mean * mean + 1e-5f);

    float val = 0.f;
    if (lane < KK)
        val = (p0[bc * KK + lane] - mean) * rstd * ln0w[c * KK + lane]
              + ln0b[c * KK + lane];

    int i0 = lane / KS;
    int j0 = lane - i0 * KS;
    const float* wc = w0 + c * KK;

    float acc = 0.f;
#pragma unroll
    for (int u = 0; u < KS; ++u) {
        int ii = i0 + u - 3;
#pragma unroll
        for (int v = 0; v < KS; ++v) {
            int jj = j0 + v - 3;
            bool ok = (ii >= 0) && (ii < KS) && (jj >= 0) && (jj < KS);
            int sl = ok ? (ii * KS + jj) : 0;
            float sv = __shfl(val, sl, 64);
            acc += ok ? sv * wc[u * KS + v] : 0.f;
        }
    }
    if (lane >= KK) acc = 0.f;
    if (lane < KK) q1[bc * KK + lane] = acc;

    float s2 = acc, ss2 = acc * acc;
#pragma unroll
    for (int o = 32; o > 0; o >>= 1) {
        s2  += __shfl_down(s2, o, 64);
        ss2 += __shfl_down(ss2, o, 64);
    }
    if (lane == 0) {
        red[(tid >> 6) * 2 + 0] = s2;
        red[(tid >> 6) * 2 + 1] = ss2;
    }
    __syncthreads();
    if (tid == 0) {
        float a = 0.f, q = 0.f;
#pragma unroll
        for (int w = 0; w < 8; ++w) { a += red[2 * w]; q += red[2 * w + 1]; }
        part1[blockIdx.x] = make_float2(a, q);
    }
}

// ---------------------------------------------------------------------------
// K3: fused LN1+ReLU taps + per-(b,c) depthwise 7x7 SAME conv.
// Row-pair-packed LDS (R10-verified layout/staging/tap algebra), NEW mapping:
// 2 waves/block; lane = (cp 0..27, rh 0..1); lane computes cols {2cp, 2cp+1}
// x 14 rows (rh half). Window cells 2cp..2cp+7 read as 4x ds_read_b128.
// Cell j: lo/hi rows feed col A with taps v=j (dl/dh by parity) and col B
// with v=j-1; cross terms via op_sel-swapped pkfma_x. Taps in SGPR pairs.
// ---------------------------------------------------------------------------
#define TW2 64

__device__ __forceinline__ float rfl(float v) {
    return __int_as_float(__builtin_amdgcn_readfirstlane(__float_as_int(v)));
}

// acc.lo += vp.lo*tp.lo ; acc.hi += vp.hi*tp.lo   (diag, tap lo)
__device__ __forceinline__ void pkfma_dl(f2& acc, f2 vp, f2 tp) {
    asm("v_pk_fma_f32 %0, %1, %2, %0 op_sel_hi:[1,0,1]"
        : "+v"(acc) : "v"(vp), "s"(tp));
}
// acc.lo += vp.lo*tp.hi ; acc.hi += vp.hi*tp.hi   (diag, tap hi)
__device__ __forceinline__ void pkfma_dh(f2& acc, f2 vp, f2 tp) {
    asm("v_pk_fma_f32 %0, %1, %2, %0 op_sel:[0,1,0] op_sel_hi:[1,1,1]"
        : "+v"(acc) : "v"(vp), "s"(tp));
}
// acc.lo += vp.hi*tp.lo ; acc.hi += vp.lo*tp.hi   (cross, swapped rows)
__device__ __forceinline__ void pkfma_x(f2& acc, f2 vp, f2 tp) {
    asm("v_pk_fma_f32 %0, %1, %2, %0 op_sel:[1,0,0] op_sel_hi:[0,1,1]"
        : "+v"(acc) : "v"(vp), "s"(tp));
}

__global__ __launch_bounds__(128) void conv_kernel(
    const float* __restrict__ x,
    const float* __restrict__ q1, const float2* __restrict__ part1,
    const float* __restrict__ ln1w, const float* __restrict__ ln1b,
    float* __restrict__ out)
{
    __shared__ f2 tile2[32 * TW2];   // pair pr2 = padded rows {2pr2, 2pr2+1}
    __shared__ float kt[KK];
    __shared__ f2 dtab[16];
    __shared__ f2 ctab[28];
    int bc   = blockIdx.x;
    int b    = bc / CC;
    int c    = bc - b * CC;
    int tid  = threadIdx.x;
    int lane = tid & 63;
    int wid  = tid >> 6;

    // ---- stats1 from 24 partials (every wave) ----
    float s1 = 0.f, ss1 = 0.f;
    if (lane < MIDBLK) {
        float2 p = part1[b * MIDBLK + lane];
        s1 = p.x; ss1 = p.y;
    }
#pragma unroll
    for (int o = 32; o > 0; o >>= 1) {
        s1  += __shfl_down(s1, o, 64);
        ss1 += __shfl_down(ss1, o, 64);
    }
    s1  = __shfl(s1, 0, 64);
    ss1 = __shfl(ss1, 0, 64);

    // ---- taps: LN1 + ReLU on q1 ----
    if (tid < KK) {
        float m = s1 * (1.f / CKK);
        float r = rsqrtf(ss1 * (1.f / CKK) - m * m + 1e-5f);
        float v = (q1[(size_t)bc * KK + tid] - m) * r * ln1w[c * KK + tid]
                  + ln1b[c * KK + tid];
        kt[tid] = v > 0.f ? v : 0.f;
    }

    // ---- zero the packed tile ----
    for (int i = tid; i < 32 * TW2 / 2; i += 128)
        ((float4*)tile2)[i] = make_float4(0.f, 0.f, 0.f, 0.f);
    __syncthreads();   // kt + zeros visible

    // ---- tap pair tables (R10-verified) ----
    if (tid < 28) {
        int d = tid / KS, v = tid - KS * d;
        f2 p;
        p.x = (d < 3) ? kt[(2 * d + 1) * KS + v] : 0.f;
        p.y = (d > 0) ? kt[(2 * d - 1) * KS + v] : 0.f;
        ctab[tid] = p;
    } else if (tid < 44) {
        int t = tid - 28;
        int d = t / 4, j = t - 4 * d;
        f2 p;
        p.x = kt[2 * d * KS + 2 * j];
        p.y = (2 * j + 1 < KS) ? kt[2 * d * KS + 2 * j + 1] : 0.f;
        dtab[t] = p;
    }

    // ---- stage x as row pairs, LEFT PAD 3 (R10-verified pattern) ----
    const float* src = x + (size_t)bc * HW;
    for (int i = tid; i < 29 * 14; i += 128) {
        int pr2 = 1 + i / 14;
        int q   = i - (pr2 - 1) * 14;
        int rA  = 2 * pr2 - 3;            // odd x row (or -1)
        int rB  = rA + 1;                 // even x row (or 56)
        float4 a4 = (rA >= 0) ? *(const float4*)(src + rA * WW + 4 * q)
                              : make_float4(0.f, 0.f, 0.f, 0.f);
        float4 b4 = (rB < HH) ? *(const float4*)(src + rB * WW + 4 * q)
                              : make_float4(0.f, 0.f, 0.f, 0.f);
        f2* cell = tile2 + pr2 * TW2 + 3 + 4 * q;
        cell[0] = (f2){a4.x, b4.x};
        cell[1] = (f2){a4.y, b4.y};
        cell[2] = (f2){a4.z, b4.z};
        cell[3] = (f2){a4.w, b4.w};
    }
    __syncthreads();

    // ---- tap tables -> SGPR pairs ----
    f2 dp[16], cpx[28];
#pragma unroll
    for (int i = 0; i < 8; ++i) {
        float4 t4 = ((const float4*)dtab)[i];
        dp[2 * i]     = (f2){rfl(t4.x), rfl(t4.y)};
        dp[2 * i + 1] = (f2){rfl(t4.z), rfl(t4.w)};
    }
#pragma unroll
    for (int i = 0; i < 14; ++i) {
        float4 t4 = ((const float4*)ctab)[i];
        cpx[2 * i]     = (f2){rfl(t4.x), rfl(t4.y)};
        cpx[2 * i + 1] = (f2){rfl(t4.z), rfl(t4.w)};
    }

    // ---- lane mapping: (cp, rh); 2 cols x 14 rows per lane ----
    int rh = lane / 28;  if (rh > 1) rh = 1;     // lanes 56-63: dup, masked
    int cp = lane - 28 * (lane / 28); if (cp > 27) cp = 27;
    int R2 = wid * 14 + rh * 7;                  // first rowpair of this half

    f2 accA[7], accB[7];
#pragma unroll
    for (int t = 0; t < 7; ++t) { accA[t] = (f2){0.f, 0.f}; accB[t] = (f2){0.f, 0.f}; }

#pragma unroll
    for (int s = 0; s < 10; ++s) {
        const float4* rp = (const float4*)(tile2 + (R2 + s) * TW2 + 2 * cp);
        float4 q0 = rp[0], q1v = rp[1], q2 = rp[2], q3 = rp[3];
        f2 v2[8];
        v2[0] = (f2){q0.x, q0.y}; v2[1] = (f2){q0.z, q0.w};
        v2[2] = (f2){q1v.x, q1v.y}; v2[3] = (f2){q1v.z, q1v.w};
        v2[4] = (f2){q2.x, q2.y}; v2[5] = (f2){q2.z, q2.w};
        v2[6] = (f2){q3.x, q3.y}; v2[7] = (f2){q3.z, q3.w};
#pragma unroll
        for (int d = 0; d < 4; ++d) {
            int t = s - d;                       // static after unroll
            if (t < 0 || t > 6) continue;
#pragma unroll
            for (int j = 0; j < 7; ++j) {        // col A: v = j
                if (j & 1) pkfma_dh(accA[t], v2[j], dp[d * 4 + (j >> 1)]);
                else       pkfma_dl(accA[t], v2[j], dp[d * 4 + (j >> 1)]);
                pkfma_x(accA[t], v2[j], cpx[d * KS + j]);
            }
#pragma unroll
            for (int j = 1; j < 8; ++j) {        // col B: v = j-1
                int v = j - 1;
                if (v & 1) pkfma_dh(accB[t], v2[j], dp[d * 4 + (v >> 1)]);
                else       pkfma_dl(accB[t], v2[j], dp[d * 4 + (v >> 1)]);
                pkfma_x(accB[t], v2[j], cpx[d * KS + v]);
            }
        }
    }

    if (lane < 56) {
        float* ob = out + (size_t)bc * HW;
        int col = 2 * cp;
        int rowbase = wid * 28 + rh * 14;
#pragma unroll
        for (int t = 0; t < 7; ++t) {
            *(float2*)(ob + (rowbase + 2 * t) * WW + col) =
                make_float2(accA[t].x, accB[t].x);
            *(float2*)(ob + (rowbase + 2 * t + 1) * WW + col) =
                make_float2(accA[t].y, accB[t].y);
        }
    }
}

// ---------------------------------------------------------------------------
extern "C" void kernel_launch(void* const* d_in, const int* in_sizes, int n_in,
                              void* d_out, int out_size, void* d_ws, size_t ws_size,
                              hipStream_t stream) {
    const float* x    = (const float*)d_in[0];
    const float* ln0w = (const float*)d_in[1];
    const float* ln0b = (const float*)d_in[2];
    const float* w0   = (const float*)d_in[3];
    const float* ln1w = (const float*)d_in[4];
    const float* ln1b = (const float*)d_in[5];
    float* out = (float*)d_out;

    float*  p0    = (float*)d_ws;                    // [NCELL]
    float*  q1    = p0 + NCELL;                      // [NCELL]
    float2* part0 = (float2*)(q1 + NCELL);           // [BB*P0BLK]
    float2* part1 = part0 + BB * P0BLK;              // [BB*MIDBLK]

    pool_kernel<<<BB * P0BLK, 256, 0, stream>>>(x, p0, part0);
    mid_kernel <<<BB * MIDBLK, 512, 0, stream>>>(p0, ln0w, ln0b, w0, part0, q1, part1);
    conv_kernel<<<NBC, 128, 0, stream>>>(x, q1, part1, ln1w, ln1b, out);
}

// Round 12
// 69.543 us; speedup vs baseline: 1.0310x; 1.0310x over previous
//
#include <hip/hip_runtime.h>

// Problem constants (B,C,H,W,K) = (32,192,56,56,7)
#define BB 32
#define CC 192
#define HH 56
#define WW 56
#define KS 7
#define HW 3136        // 56*56
#define KK 49
#define CKK 9408       // C*K*K
#define PL 8
#define NCELL (BB * CC * KK)   // 301056
#define NBC (BB * CC)          // 6144
#define P0BLK 37               // pool blocks per sample
#define MIDBLK 24              // mid blocks per sample

typedef float f2 __attribute__((ext_vector_type(2)));

// ---------------------------------------------------------------------------
// K1: avg pool 56x56 -> 7x7 + per-block LN0 partials (no atomics).
// ---------------------------------------------------------------------------
__global__ __launch_bounds__(256) void pool_kernel(const float* __restrict__ x,
                                                   float* __restrict__ p0,
                                                   float2* __restrict__ part0) {
    __shared__ float red[8];
    int b = blockIdx.x / P0BLK;
    int t = blockIdx.x - b * P0BLK;
    int cell = t * 256 + threadIdx.x;
    float v = 0.f;
    if (cell < CKK) {
        int c = cell / KK;
        int r = cell - c * KK;
        int i = r / KS;
        int j = r - i * KS;
        const float* src = x + ((size_t)(b * CC + c)) * HW + (i * PL) * WW + j * PL;
        float s = 0.f;
#pragma unroll
        for (int a = 0; a < PL; ++a) {
            float4 v0 = *(const float4*)(src + a * WW);
            float4 v1 = *(const float4*)(src + a * WW + 4);
            s += v0.x + v0.y + v0.z + v0.w + v1.x + v1.y + v1.z + v1.w;
        }
        v = s * (1.f / 64.f);
        p0[b * CKK + cell] = v;
    }
    float sv = v, sq = v * v;
#pragma unroll
    for (int o = 32; o > 0; o >>= 1) {
        sv += __shfl_down(sv, o, 64);
        sq += __shfl_down(sq, o, 64);
    }
    if ((threadIdx.x & 63) == 0) {
        red[(threadIdx.x >> 6) * 2 + 0] = sv;
        red[(threadIdx.x >> 6) * 2 + 1] = sq;
    }
    __syncthreads();
    if (threadIdx.x == 0)
        part0[blockIdx.x] = make_float2(red[0] + red[2] + red[4] + red[6],
                                        red[1] + red[3] + red[5] + red[7]);
}

// ---------------------------------------------------------------------------
// K2: LN0-normalize + depthwise 7x7 conv on the 7x7 map, one WAVE per (b,c).
// ---------------------------------------------------------------------------
__global__ __launch_bounds__(512) void mid_kernel(
    const float* __restrict__ p0,
    const float* __restrict__ ln0w, const float* __restrict__ ln0b,
    const float* __restrict__ w0,
    const float2* __restrict__ part0,
    float* __restrict__ q1,
    float2* __restrict__ part1)
{
    __shared__ float red[16];
    int tid  = threadIdx.x;
    int lane = tid & 63;
    int bc   = blockIdx.x * 8 + (tid >> 6);
    int b = bc / CC;
    int c = bc - b * CC;

    float s0 = 0.f, ss0 = 0.f;
    if (lane < P0BLK) {
        float2 p = part0[b * P0BLK + lane];
        s0 = p.x; ss0 = p.y;
    }
#pragma unroll
    for (int o = 32; o > 0; o >>= 1) {
        s0  += __shfl_down(s0, o, 64);
        ss0 += __shfl_down(ss0, o, 64);
    }
    s0  = __shfl(s0, 0, 64);
    ss0 = __shfl(ss0, 0, 64);
    float mean = s0 * (1.f / CKK);
    float rstd = rsqrtf(ss0 * (1.f / CKK) - mean * mean + 1e-5f);

    float val = 0.f;
    if (lane < KK)
        val = (p0[bc * KK + lane] - mean) * rstd * ln0w[c * KK + lane]
              + ln0b[c * KK + lane];

    int i0 = lane / KS;
    int j0 = lane - i0 * KS;
    const float* wc = w0 + c * KK;

    float acc = 0.f;
#pragma unroll
    for (int u = 0; u < KS; ++u) {
        int ii = i0 + u - 3;
#pragma unroll
        for (int v = 0; v < KS; ++v) {
            int jj = j0 + v - 3;
            bool ok = (ii >= 0) && (ii < KS) && (jj >= 0) && (jj < KS);
            int sl = ok ? (ii * KS + jj) : 0;
            float sv = __shfl(val, sl, 64);
            acc += ok ? sv * wc[u * KS + v] : 0.f;
        }
    }
    if (lane >= KK) acc = 0.f;
    if (lane < KK) q1[bc * KK + lane] = acc;

    float s2 = acc, ss2 = acc * acc;
#pragma unroll
    for (int o = 32; o > 0; o >>= 1) {
        s2  += __shfl_down(s2, o, 64);
        ss2 += __shfl_down(ss2, o, 64);
    }
    if (lane == 0) {
        red[(tid >> 6) * 2 + 0] = s2;
        red[(tid >> 6) * 2 + 1] = ss2;
    }
    __syncthreads();
    if (tid == 0) {
        float a = 0.f, q = 0.f;
#pragma unroll
        for (int w = 0; w < 8; ++w) { a += red[2 * w]; q += red[2 * w + 1]; }
        part1[blockIdx.x] = make_float2(a, q);
    }
}

// ---------------------------------------------------------------------------
// K3: tab_kernel — LN1+ReLU on q1 and dtab/ctab construction, one wave per bc
// (4 bc per 256-thr block), all in-wave via __shfl. tab[bc] = 44 f2:
//   [0..15]  dtab[d*4+j] = {kt[2d*7+2j], kt[2d*7+2j+1]|0}
//   [16..43] ctab[d*7+v] = {kt[(2d+1)*7+v]|0, kt[(2d-1)*7+v]|0}
// ---------------------------------------------------------------------------
__global__ __launch_bounds__(256) void tab_kernel(
    const float* __restrict__ q1, const float2* __restrict__ part1,
    const float* __restrict__ ln1w, const float* __restrict__ ln1b,
    f2* __restrict__ tab)
{
    int lane = threadIdx.x & 63;
    int bc   = blockIdx.x * 4 + (threadIdx.x >> 6);
    int b = bc / CC;
    int c = bc - b * CC;

    float s1 = 0.f, ss1 = 0.f;
    if (lane < MIDBLK) {
        float2 p = part1[b * MIDBLK + lane];
        s1 = p.x; ss1 = p.y;
    }
#pragma unroll
    for (int o = 32; o > 0; o >>= 1) {
        s1  += __shfl_down(s1, o, 64);
        ss1 += __shfl_down(ss1, o, 64);
    }
    s1  = __shfl(s1, 0, 64);
    ss1 = __shfl(ss1, 0, 64);
    float m = s1 * (1.f / CKK);
    float r = rsqrtf(ss1 * (1.f / CKK) - m * m + 1e-5f);

    float kt = 0.f;
    if (lane < KK) {
        float v = (q1[(size_t)bc * KK + lane] - m) * r * ln1w[c * KK + lane]
                  + ln1b[c * KK + lane];
        kt = v > 0.f ? v : 0.f;
    }

    // per-lane gather indices for the two table halves
    int iA = 0, iB = 0;
    bool mA = false, mB = false;
    if (lane < 28) {                       // ctab entry `lane`
        int d = lane / KS, v = lane - KS * d;
        mA = (d < 3); iA = mA ? (2 * d + 1) * KS + v : 0;
        mB = (d > 0); iB = mB ? (2 * d - 1) * KS + v : 0;
    } else if (lane < 44) {                // dtab entry lane-28
        int t = lane - 28;
        int d = t >> 2, j = t & 3;
        mA = true;     iA = 2 * d * KS + 2 * j;
        mB = (j < 3);  iB = mB ? 2 * d * KS + 2 * j + 1 : 0;
    }
    float va = __shfl(kt, iA, 64);
    float vb = __shfl(kt, iB, 64);
    f2 p;
    p.x = mA ? va : 0.f;
    p.y = mB ? vb : 0.f;

    f2* row = tab + (size_t)bc * 44;
    if (lane < 28)      row[16 + lane] = p;
    else if (lane < 44) row[lane - 28] = p;
}

// ---------------------------------------------------------------------------
// K4: per-(b,c) depthwise 7x7 SAME conv. R10-verified main loop (row-pair
// packed cells, ds_read_b64, pkfma dl/dh/x with SGPR-pair taps). Prologue is
// now just block-uniform tab loads (-> s_load) + async-staged tile fill.
// ---------------------------------------------------------------------------
#define TW2 64

// acc.lo += vp.lo*tp.lo ; acc.hi += vp.hi*tp.lo   (diag, tap lo)
__device__ __forceinline__ void pkfma_dl(f2& acc, f2 vp, f2 tp) {
    asm("v_pk_fma_f32 %0, %1, %2, %0 op_sel_hi:[1,0,1]"
        : "+v"(acc) : "v"(vp), "s"(tp));
}
// acc.lo += vp.lo*tp.hi ; acc.hi += vp.hi*tp.hi   (diag, tap hi)
__device__ __forceinline__ void pkfma_dh(f2& acc, f2 vp, f2 tp) {
    asm("v_pk_fma_f32 %0, %1, %2, %0 op_sel:[0,1,0] op_sel_hi:[1,1,1]"
        : "+v"(acc) : "v"(vp), "s"(tp));
}
// acc.lo += vp.hi*tp.lo ; acc.hi += vp.lo*tp.hi   (cross, swapped rows)
__device__ __forceinline__ void pkfma_x(f2& acc, f2 vp, f2 tp) {
    asm("v_pk_fma_f32 %0, %1, %2, %0 op_sel:[1,0,0] op_sel_hi:[0,1,1]"
        : "+v"(acc) : "v"(vp), "s"(tp));
}

__global__ __launch_bounds__(256) void conv_kernel(
    const float* __restrict__ x,
    const f2* __restrict__ tab,
    float* __restrict__ out)
{
    __shared__ f2 tile2[32 * TW2];   // pair pr2 = padded rows {2pr2, 2pr2+1}
    int bc   = blockIdx.x;
    int tid  = threadIdx.x;
    int lane = tid & 63;
    int wid  = tid >> 6;

    // ---- block-uniform tap tables -> SGPRs (scalarized loads) ----
    const float4* tb4 = (const float4*)(tab + (size_t)bc * 44);
    f2 dp[16], cpx[28];
#pragma unroll
    for (int i = 0; i < 8; ++i) {
        float4 t4 = tb4[i];
        dp[2 * i]     = (f2){t4.x, t4.y};
        dp[2 * i + 1] = (f2){t4.z, t4.w};
    }
#pragma unroll
    for (int i = 0; i < 14; ++i) {
        float4 t4 = tb4[8 + i];
        cpx[2 * i]     = (f2){t4.x, t4.y};
        cpx[2 * i + 1] = (f2){t4.z, t4.w};
    }

    // ---- async stage: issue global loads for both tasks ----
    const float* src = x + (size_t)bc * HW;
    int t0 = tid, t1 = tid + 256;                 // tasks 0..405
    int pr2a = 1 + t0 / 14, qa = t0 - (pr2a - 1) * 14;
    int pr2b = 1 + t1 / 14, qb = t1 - (pr2b - 1) * 14;
    int rAa = 2 * pr2a - 3, rBa = rAa + 1;
    int rAb = 2 * pr2b - 3, rBb = rAb + 1;
    float4 z4 = make_float4(0.f, 0.f, 0.f, 0.f);
    float4 a0 = (rAa >= 0) ? *(const float4*)(src + rAa * WW + 4 * qa) : z4;
    float4 b0 = (rBa < HH) ? *(const float4*)(src + rBa * WW + 4 * qa) : z4;
    float4 a1 = z4, b1 = z4;
    if (t1 < 29 * 14) {
        a1 = *(const float4*)(src + rAb * WW + 4 * qb);            // rAb >= 33
        b1 = (rBb < HH) ? *(const float4*)(src + rBb * WW + 4 * qb) : z4;
    }

    // ---- zero tile while stage loads are in flight ----
    for (int i = tid; i < 32 * TW2 / 2; i += 256)
        ((float4*)tile2)[i] = z4;
    __syncthreads();

    // ---- write staged row pairs ----
    {
        f2* cell = tile2 + pr2a * TW2 + 3 + 4 * qa;
        cell[0] = (f2){a0.x, b0.x};
        cell[1] = (f2){a0.y, b0.y};
        cell[2] = (f2){a0.z, b0.z};
        cell[3] = (f2){a0.w, b0.w};
    }
    if (t1 < 29 * 14) {
        f2* cell = tile2 + pr2b * TW2 + 3 + 4 * qb;
        cell[0] = (f2){a1.x, b1.x};
        cell[1] = (f2){a1.y, b1.y};
        cell[2] = (f2){a1.z, b1.z};
        cell[3] = (f2){a1.w, b1.w};
    }
    __syncthreads();

    // ---- main loop (R10-verified): 10 row-pair steps, acc forwarding ----
    int r0 = wid * 14;
    int R2 = wid * 7;
    f2 acc2[7];
#pragma unroll
    for (int t = 0; t < 7; ++t) acc2[t] = (f2){0.f, 0.f};

#pragma unroll
    for (int s = 0; s < 10; ++s) {
        const f2* cellp = tile2 + (R2 + s) * TW2 + lane;
        f2 v2[KS];
#pragma unroll
        for (int j = 0; j < KS; ++j) v2[j] = cellp[j];   // ds_read_b64
#pragma unroll
        for (int d = 0; d < 4; ++d) {
            int t = s - d;                               // static after unroll
            if (t < 0 || t > 6) continue;
#pragma unroll
            for (int v = 0; v < KS; ++v) {
                if (v & 1) pkfma_dh(acc2[t], v2[v], dp[d * 4 + (v >> 1)]);
                else       pkfma_dl(acc2[t], v2[v], dp[d * 4 + (v >> 1)]);
                pkfma_x(acc2[t], v2[v], cpx[d * KS + v]);
            }
        }
    }

    if (lane < WW) {
        float* ob = out + (size_t)bc * HW + r0 * WW + lane;
#pragma unroll
        for (int t = 0; t < 7; ++t) {
            ob[(2 * t) * WW]     = acc2[t].x;
            ob[(2 * t + 1) * WW] = acc2[t].y;
        }
    }
}

// ---------------------------------------------------------------------------
extern "C" void kernel_launch(void* const* d_in, const int* in_sizes, int n_in,
                              void* d_out, int out_size, void* d_ws, size_t ws_size,
                              hipStream_t stream) {
    const float* x    = (const float*)d_in[0];
    const float* ln0w = (const float*)d_in[1];
    const float* ln0b = (const float*)d_in[2];
    const float* w0   = (const float*)d_in[3];
    const float* ln1w = (const float*)d_in[4];
    const float* ln1b = (const float*)d_in[5];
    float* out = (float*)d_out;

    float*  p0    = (float*)d_ws;                    // [NCELL]
    float*  q1    = p0 + NCELL;                      // [NCELL]
    float2* part0 = (float2*)(q1 + NCELL);           // [BB*P0BLK]
    float2* part1 = part0 + BB * P0BLK;              // [BB*MIDBLK]
    f2*     tab   = (f2*)(part1 + BB * MIDBLK);      // [NBC*44]

    pool_kernel<<<BB * P0BLK, 256, 0, stream>>>(x, p0, part0);
    mid_kernel <<<BB * MIDBLK, 512, 0, stream>>>(p0, ln0w, ln0b, w0, part0, q1, part1);
    tab_kernel <<<NBC / 4, 256, 0, stream>>>(q1, part1, ln1w, ln1b, tab);
    conv_kernel<<<NBC, 256, 0, stream>>>(x, tab, out);
}

// Round 13
// 65.309 us; speedup vs baseline: 1.0979x; 1.0648x over previous
//
#include <hip/hip_runtime.h>

// Problem constants (B,C,H,W,K) = (32,192,56,56,7)
#define BB 32
#define CC 192
#define HH 56
#define WW 56
#define KS 7
#define HW 3136        // 56*56
#define KK 49
#define CKK 9408       // C*K*K
#define PL 8
#define NCELL (BB * CC * KK)   // 301056
#define NBC (BB * CC)          // 6144
#define P0BLK 37               // pool blocks per sample
#define MIDBLK 24              // mid blocks per sample

typedef float f2 __attribute__((ext_vector_type(2)));

// ---------------------------------------------------------------------------
// K1: avg pool 56x56 -> 7x7 + per-block LN0 partials (no atomics).
// ---------------------------------------------------------------------------
__global__ __launch_bounds__(256) void pool_kernel(const float* __restrict__ x,
                                                   float* __restrict__ p0,
                                                   float2* __restrict__ part0) {
    __shared__ float red[8];
    int b = blockIdx.x / P0BLK;
    int t = blockIdx.x - b * P0BLK;
    int cell = t * 256 + threadIdx.x;
    float v = 0.f;
    if (cell < CKK) {
        int c = cell / KK;
        int r = cell - c * KK;
        int i = r / KS;
        int j = r - i * KS;
        const float* src = x + ((size_t)(b * CC + c)) * HW + (i * PL) * WW + j * PL;
        float s = 0.f;
#pragma unroll
        for (int a = 0; a < PL; ++a) {
            float4 v0 = *(const float4*)(src + a * WW);
            float4 v1 = *(const float4*)(src + a * WW + 4);
            s += v0.x + v0.y + v0.z + v0.w + v1.x + v1.y + v1.z + v1.w;
        }
        v = s * (1.f / 64.f);
        p0[b * CKK + cell] = v;
    }
    float sv = v, sq = v * v;
#pragma unroll
    for (int o = 32; o > 0; o >>= 1) {
        sv += __shfl_down(sv, o, 64);
        sq += __shfl_down(sq, o, 64);
    }
    if ((threadIdx.x & 63) == 0) {
        red[(threadIdx.x >> 6) * 2 + 0] = sv;
        red[(threadIdx.x >> 6) * 2 + 1] = sq;
    }
    __syncthreads();
    if (threadIdx.x == 0)
        part0[blockIdx.x] = make_float2(red[0] + red[2] + red[4] + red[6],
                                        red[1] + red[3] + red[5] + red[7]);
}

// ---------------------------------------------------------------------------
// K2: LN0-normalize + depthwise 7x7 conv on the 7x7 map, one WAVE per (b,c).
// ---------------------------------------------------------------------------
__global__ __launch_bounds__(512) void mid_kernel(
    const float* __restrict__ p0,
    const float* __restrict__ ln0w, const float* __restrict__ ln0b,
    const float* __restrict__ w0,
    const float2* __restrict__ part0,
    float* __restrict__ q1,
    float2* __restrict__ part1)
{
    __shared__ float red[16];
    int tid  = threadIdx.x;
    int lane = tid & 63;
    int bc   = blockIdx.x * 8 + (tid >> 6);
    int b = bc / CC;
    int c = bc - b * CC;

    float s0 = 0.f, ss0 = 0.f;
    if (lane < P0BLK) {
        float2 p = part0[b * P0BLK + lane];
        s0 = p.x; ss0 = p.y;
    }
#pragma unroll
    for (int o = 32; o > 0; o >>= 1) {
        s0  += __shfl_down(s0, o, 64);
        ss0 += __shfl_down(ss0, o, 64);
    }
    s0  = __shfl(s0, 0, 64);
    ss0 = __shfl(ss0, 0, 64);
    float mean = s0 * (1.f / CKK);
    float rstd = rsqrtf(ss0 * (1.f / CKK) - mean * mean + 1e-5f);

    float val = 0.f;
    if (lane < KK)
        val = (p0[bc * KK + lane] - mean) * rstd * ln0w[c * KK + lane]
              + ln0b[c * KK + lane];

    int i0 = lane / KS;
    int j0 = lane - i0 * KS;
    const float* wc = w0 + c * KK;

    float acc = 0.f;
#pragma unroll
    for (int u = 0; u < KS; ++u) {
        int ii = i0 + u - 3;
#pragma unroll
        for (int v = 0; v < KS; ++v) {
            int jj = j0 + v - 3;
            bool ok = (ii >= 0) && (ii < KS) && (jj >= 0) && (jj < KS);
            int sl = ok ? (ii * KS + jj) : 0;
            float sv = __shfl(val, sl, 64);
            acc += ok ? sv * wc[u * KS + v] : 0.f;
        }
    }
    if (lane >= KK) acc = 0.f;
    if (lane < KK) q1[bc * KK + lane] = acc;

    float s2 = acc, ss2 = acc * acc;
#pragma unroll
    for (int o = 32; o > 0; o >>= 1) {
        s2  += __shfl_down(s2, o, 64);
        ss2 += __shfl_down(ss2, o, 64);
    }
    if (lane == 0) {
        red[(tid >> 6) * 2 + 0] = s2;
        red[(tid >> 6) * 2 + 1] = ss2;
    }
    __syncthreads();
    if (tid == 0) {
        float a = 0.f, q = 0.f;
#pragma unroll
        for (int w = 0; w < 8; ++w) { a += red[2 * w]; q += red[2 * w + 1]; }
        part1[blockIdx.x] = make_float2(a, q);
    }
}

// ---------------------------------------------------------------------------
// K3: tab_kernel — LN1+ReLU on q1 and dtab/ctab construction, one wave per bc.
//   tab[bc][0..15]  dtab[d*4+j] = {kt[2d*7+2j], kt[2d*7+2j+1]|0}
//   tab[bc][16..43] ctab[d*7+v] = {kt[(2d+1)*7+v]|0, kt[(2d-1)*7+v]|0}
// ---------------------------------------------------------------------------
__global__ __launch_bounds__(256) void tab_kernel(
    const float* __restrict__ q1, const float2* __restrict__ part1,
    const float* __restrict__ ln1w, const float* __restrict__ ln1b,
    f2* __restrict__ tab)
{
    int lane = threadIdx.x & 63;
    int bc   = blockIdx.x * 4 + (threadIdx.x >> 6);
    int b = bc / CC;
    int c = bc - b * CC;

    float s1 = 0.f, ss1 = 0.f;
    if (lane < MIDBLK) {
        float2 p = part1[b * MIDBLK + lane];
        s1 = p.x; ss1 = p.y;
    }
#pragma unroll
    for (int o = 32; o > 0; o >>= 1) {
        s1  += __shfl_down(s1, o, 64);
        ss1 += __shfl_down(ss1, o, 64);
    }
    s1  = __shfl(s1, 0, 64);
    ss1 = __shfl(ss1, 0, 64);
    float m = s1 * (1.f / CKK);
    float r = rsqrtf(ss1 * (1.f / CKK) - m * m + 1e-5f);

    float kt = 0.f;
    if (lane < KK) {
        float v = (q1[(size_t)bc * KK + lane] - m) * r * ln1w[c * KK + lane]
                  + ln1b[c * KK + lane];
        kt = v > 0.f ? v : 0.f;
    }

    int iA = 0, iB = 0;
    bool mA = false, mB = false;
    if (lane < 28) {
        int d = lane / KS, v = lane - KS * d;
        mA = (d < 3); iA = mA ? (2 * d + 1) * KS + v : 0;
        mB = (d > 0); iB = mB ? (2 * d - 1) * KS + v : 0;
    } else if (lane < 44) {
        int t = lane - 28;
        int d = t >> 2, j = t & 3;
        mA = true;     iA = 2 * d * KS + 2 * j;
        mB = (j < 3);  iB = mB ? 2 * d * KS + 2 * j + 1 : 0;
    }
    float va = __shfl(kt, iA, 64);
    float vb = __shfl(kt, iB, 64);
    f2 p;
    p.x = mA ? va : 0.f;
    p.y = mB ? vb : 0.f;

    f2* row = tab + (size_t)bc * 44;
    if (lane < 28)      row[16 + lane] = p;
    else if (lane < 44) row[lane - 28] = p;
}

// ---------------------------------------------------------------------------
// K4: per-(b,c) depthwise 7x7 SAME conv. R10-verified algebra; NEW schedule:
// single barrier (halo-only zero + staged writes disjoint), ping-pong
// prefetched main loop (reads for rowpair s+1 issued before compute on s).
// ---------------------------------------------------------------------------
#define TW2 64

// acc.lo += vp.lo*tp.lo ; acc.hi += vp.hi*tp.lo   (diag, tap lo)
__device__ __forceinline__ void pkfma_dl(f2& acc, f2 vp, f2 tp) {
    asm("v_pk_fma_f32 %0, %1, %2, %0 op_sel_hi:[1,0,1]"
        : "+v"(acc) : "v"(vp), "s"(tp));
}
// acc.lo += vp.lo*tp.hi ; acc.hi += vp.hi*tp.hi   (diag, tap hi)
__device__ __forceinline__ void pkfma_dh(f2& acc, f2 vp, f2 tp) {
    asm("v_pk_fma_f32 %0, %1, %2, %0 op_sel:[0,1,0] op_sel_hi:[1,1,1]"
        : "+v"(acc) : "v"(vp), "s"(tp));
}
// acc.lo += vp.hi*tp.lo ; acc.hi += vp.lo*tp.hi   (cross, swapped rows)
__device__ __forceinline__ void pkfma_x(f2& acc, f2 vp, f2 tp) {
    asm("v_pk_fma_f32 %0, %1, %2, %0 op_sel:[1,0,0] op_sel_hi:[0,1,1]"
        : "+v"(acc) : "v"(vp), "s"(tp));
}

__global__ __launch_bounds__(256) void conv_kernel(
    const float* __restrict__ x,
    const f2* __restrict__ tab,
    float* __restrict__ out)
{
    __shared__ f2 tile2[32 * TW2];   // pair pr2 = padded rows {2pr2, 2pr2+1}
    int bc   = blockIdx.x;
    int tid  = threadIdx.x;
    int lane = tid & 63;
    int wid  = tid >> 6;

    // ---- block-uniform tap tables -> SGPRs ----
    const float4* tb4 = (const float4*)(tab + (size_t)bc * 44);
    f2 dp[16], cpx[28];
#pragma unroll
    for (int i = 0; i < 8; ++i) {
        float4 t4 = tb4[i];
        dp[2 * i]     = (f2){t4.x, t4.y};
        dp[2 * i + 1] = (f2){t4.z, t4.w};
    }
#pragma unroll
    for (int i = 0; i < 14; ++i) {
        float4 t4 = tb4[8 + i];
        cpx[2 * i]     = (f2){t4.x, t4.y};
        cpx[2 * i + 1] = (f2){t4.z, t4.w};
    }

    // ---- issue global stage loads (2 row-pair tasks per thread) ----
    const float* src = x + (size_t)bc * HW;
    int t0 = tid, t1 = tid + 256;                 // tasks 0..405
    int pr2a = 1 + t0 / 14, qa = t0 - (pr2a - 1) * 14;
    int pr2b = 1 + t1 / 14, qb = t1 - (pr2b - 1) * 14;
    int rAa = 2 * pr2a - 3, rBa = rAa + 1;
    int rAb = 2 * pr2b - 3, rBb = rAb + 1;
    float4 z4 = make_float4(0.f, 0.f, 0.f, 0.f);
    float4 a0 = (rAa >= 0) ? *(const float4*)(src + rAa * WW + 4 * qa) : z4;
    float4 b0 = (rBa < HH) ? *(const float4*)(src + rBa * WW + 4 * qa) : z4;
    float4 a1 = z4, b1 = z4;
    if (t1 < 29 * 14) {
        a1 = *(const float4*)(src + rAb * WW + 4 * qb);            // rAb >= 33
        b1 = (rBb < HH) ? *(const float4*)(src + rBb * WW + 4 * qb) : z4;
    }

    // ---- halo-only zero (disjoint from staged cells) ----
    if (tid < 128) {                       // rowpairs 0 and 30, full width
        int pr2 = (tid < 64) ? 0 : 30;
        tile2[pr2 * TW2 + (tid & 63)] = (f2){0.f, 0.f};
    }
    if (tid < 232) {                       // edge cols of rowpairs 1..29
        int pr2 = 1 + (tid >> 3);
        int c8  = tid & 7;
        int cell = (c8 < 3) ? c8 : 56 + c8;   // 0,1,2,59,60,61,62,63
        tile2[pr2 * TW2 + cell] = (f2){0.f, 0.f};
    }

    // ---- staged writes (compiler inserts vmcnt waits) ----
    {
        f2* cell = tile2 + pr2a * TW2 + 3 + 4 * qa;
        cell[0] = (f2){a0.x, b0.x};
        cell[1] = (f2){a0.y, b0.y};
        cell[2] = (f2){a0.z, b0.z};
        cell[3] = (f2){a0.w, b0.w};
    }
    if (t1 < 29 * 14) {
        f2* cell = tile2 + pr2b * TW2 + 3 + 4 * qb;
        cell[0] = (f2){a1.x, b1.x};
        cell[1] = (f2){a1.y, b1.y};
        cell[2] = (f2){a1.z, b1.z};
        cell[3] = (f2){a1.w, b1.w};
    }
    __syncthreads();

    // ---- main loop: ping-pong prefetch, acc forwarding (R10 algebra) ----
    int r0 = wid * 14;
    const f2* base = tile2 + (wid * 7) * TW2 + lane;
    f2 acc2[7];
#pragma unroll
    for (int t = 0; t < 7; ++t) acc2[t] = (f2){0.f, 0.f};

    f2 va[KS], vb[KS];
#pragma unroll
    for (int j = 0; j < KS; ++j) va[j] = base[j];          // rowpair s=0

#define CONV_STEP(S, CUR)                                              \
    {                                                                  \
        _Pragma("unroll")                                              \
        for (int d = 0; d < 4; ++d) {                                  \
            int t = (S) - d;                                           \
            if (t >= 0 && t <= 6) {                                    \
                _Pragma("unroll")                                      \
                for (int v = 0; v < KS; ++v) {                         \
                    if (v & 1) pkfma_dh(acc2[t], CUR[v], dp[d * 4 + (v >> 1)]); \
                    else       pkfma_dl(acc2[t], CUR[v], dp[d * 4 + (v >> 1)]); \
                    pkfma_x(acc2[t], CUR[v], cpx[d * KS + v]);         \
                }                                                      \
            }                                                          \
        }                                                              \
    }

#pragma unroll
    for (int ss = 0; ss < 5; ++ss) {
        int s0 = 2 * ss, s1 = 2 * ss + 1;
        {   // prefetch rowpair s1 into vb
            const f2* np = base + s1 * TW2;
#pragma unroll
            for (int j = 0; j < KS; ++j) vb[j] = np[j];
        }
        CONV_STEP(s0, va);
        if (ss < 4) {   // prefetch rowpair s0+2 into va
            const f2* np = base + (s0 + 2) * TW2;
#pragma unroll
            for (int j = 0; j < KS; ++j) va[j] = np[j];
        }
        CONV_STEP(s1, vb);
    }
#undef CONV_STEP

    if (lane < WW) {
        float* ob = out + (size_t)bc * HW + r0 * WW + lane;
#pragma unroll
        for (int t = 0; t < 7; ++t) {
            ob[(2 * t) * WW]     = acc2[t].x;
            ob[(2 * t + 1) * WW] = acc2[t].y;
        }
    }
}

// ---------------------------------------------------------------------------
extern "C" void kernel_launch(void* const* d_in, const int* in_sizes, int n_in,
                              void* d_out, int out_size, void* d_ws, size_t ws_size,
                              hipStream_t stream) {
    const float* x    = (const float*)d_in[0];
    const float* ln0w = (const float*)d_in[1];
    const float* ln0b = (const float*)d_in[2];
    const float* w0   = (const float*)d_in[3];
    const float* ln1w = (const float*)d_in[4];
    const float* ln1b = (const float*)d_in[5];
    float* out = (float*)d_out;

    float*  p0    = (float*)d_ws;                    // [NCELL]
    float*  q1    = p0 + NCELL;                      // [NCELL]
    float2* part0 = (float2*)(q1 + NCELL);           // [BB*P0BLK]
    float2* part1 = part0 + BB * P0BLK;              // [BB*MIDBLK]
    f2*     tab   = (f2*)(part1 + BB * MIDBLK);      // [NBC*44]

    pool_kernel<<<BB * P0BLK, 256, 0, stream>>>(x, p0, part0);
    mid_kernel <<<BB * MIDBLK, 512, 0, stream>>>(p0, ln0w, ln0b, w0, part0, q1, part1);
    tab_kernel <<<NBC / 4, 256, 0, stream>>>(q1, part1, ln1w, ln1b, tab);
    conv_kernel<<<NBC, 256, 0, stream>>>(x, tab, out);
}

// Round 14
// 65.260 us; speedup vs baseline: 1.0987x; 1.0008x over previous
//
#include <hip/hip_runtime.h>

// Problem constants (B,C,H,W,K) = (32,192,56,56,7)
#define BB 32
#define CC 192
#define HH 56
#define WW 56
#define KS 7
#define HW 3136        // 56*56
#define KK 49
#define CKK 9408       // C*K*K
#define PL 8
#define NCELL (BB * CC * KK)   // 301056
#define NBC (BB * CC)          // 6144
#define P0BLK 37               // pool blocks per sample
#define MIDBLK 24              // mid blocks per sample

typedef float f2 __attribute__((ext_vector_type(2)));

// ---------------------------------------------------------------------------
// K1: avg pool 56x56 -> 7x7 + per-block LN0 partials (no atomics).
// ---------------------------------------------------------------------------
__global__ __launch_bounds__(256) void pool_kernel(const float* __restrict__ x,
                                                   float* __restrict__ p0,
                                                   float2* __restrict__ part0) {
    __shared__ float red[8];
    int b = blockIdx.x / P0BLK;
    int t = blockIdx.x - b * P0BLK;
    int cell = t * 256 + threadIdx.x;
    float v = 0.f;
    if (cell < CKK) {
        int c = cell / KK;
        int r = cell - c * KK;
        int i = r / KS;
        int j = r - i * KS;
        const float* src = x + ((size_t)(b * CC + c)) * HW + (i * PL) * WW + j * PL;
        float s = 0.f;
#pragma unroll
        for (int a = 0; a < PL; ++a) {
            float4 v0 = *(const float4*)(src + a * WW);
            float4 v1 = *(const float4*)(src + a * WW + 4);
            s += v0.x + v0.y + v0.z + v0.w + v1.x + v1.y + v1.z + v1.w;
        }
        v = s * (1.f / 64.f);
        p0[b * CKK + cell] = v;
    }
    float sv = v, sq = v * v;
#pragma unroll
    for (int o = 32; o > 0; o >>= 1) {
        sv += __shfl_down(sv, o, 64);
        sq += __shfl_down(sq, o, 64);
    }
    if ((threadIdx.x & 63) == 0) {
        red[(threadIdx.x >> 6) * 2 + 0] = sv;
        red[(threadIdx.x >> 6) * 2 + 1] = sq;
    }
    __syncthreads();
    if (threadIdx.x == 0)
        part0[blockIdx.x] = make_float2(red[0] + red[2] + red[4] + red[6],
                                        red[1] + red[3] + red[5] + red[7]);
}

// ---------------------------------------------------------------------------
// K2: LN0-normalize + depthwise 7x7 conv on the 7x7 map, one WAVE per (b,c).
// ---------------------------------------------------------------------------
__global__ __launch_bounds__(512) void mid_kernel(
    const float* __restrict__ p0,
    const float* __restrict__ ln0w, const float* __restrict__ ln0b,
    const float* __restrict__ w0,
    const float2* __restrict__ part0,
    float* __restrict__ q1,
    float2* __restrict__ part1)
{
    __shared__ float red[16];
    int tid  = threadIdx.x;
    int lane = tid & 63;
    int bc   = blockIdx.x * 8 + (tid >> 6);
    int b = bc / CC;
    int c = bc - b * CC;

    float s0 = 0.f, ss0 = 0.f;
    if (lane < P0BLK) {
        float2 p = part0[b * P0BLK + lane];
        s0 = p.x; ss0 = p.y;
    }
#pragma unroll
    for (int o = 32; o > 0; o >>= 1) {
        s0  += __shfl_down(s0, o, 64);
        ss0 += __shfl_down(ss0, o, 64);
    }
    s0  = __shfl(s0, 0, 64);
    ss0 = __shfl(ss0, 0, 64);
    float mean = s0 * (1.f / CKK);
    float rstd = rsqrtf(ss0 * (1.f / CKK) - mean * mean + 1e-5f);

    float val = 0.f;
    if (lane < KK)
        val = (p0[bc * KK + lane] - mean) * rstd * ln0w[c * KK + lane]
              + ln0b[c * KK + lane];

    int i0 = lane / KS;
    int j0 = lane - i0 * KS;
    const float* wc = w0 + c * KK;

    float acc = 0.f;
#pragma unroll
    for (int u = 0; u < KS; ++u) {
        int ii = i0 + u - 3;
#pragma unroll
        for (int v = 0; v < KS; ++v) {
            int jj = j0 + v - 3;
            bool ok = (ii >= 0) && (ii < KS) && (jj >= 0) && (jj < KS);
            int sl = ok ? (ii * KS + jj) : 0;
            float sv = __shfl(val, sl, 64);
            acc += ok ? sv * wc[u * KS + v] : 0.f;
        }
    }
    if (lane >= KK) acc = 0.f;
    if (lane < KK) q1[bc * KK + lane] = acc;

    float s2 = acc, ss2 = acc * acc;
#pragma unroll
    for (int o = 32; o > 0; o >>= 1) {
        s2  += __shfl_down(s2, o, 64);
        ss2 += __shfl_down(ss2, o, 64);
    }
    if (lane == 0) {
        red[(tid >> 6) * 2 + 0] = s2;
        red[(tid >> 6) * 2 + 1] = ss2;
    }
    __syncthreads();
    if (tid == 0) {
        float a = 0.f, q = 0.f;
#pragma unroll
        for (int w = 0; w < 8; ++w) { a += red[2 * w]; q += red[2 * w + 1]; }
        part1[blockIdx.x] = make_float2(a, q);
    }
}

// ---------------------------------------------------------------------------
// K3: tab_kernel — LN1+ReLU on q1 and dtab/ctab construction, one wave per bc.
//   tab[bc][0..15]  dtab[d*4+j] = {kt[2d*7+2j], kt[2d*7+2j+1]|0}
//   tab[bc][16..43] ctab[d*7+v] = {kt[(2d+1)*7+v]|0, kt[(2d-1)*7+v]|0}
// ---------------------------------------------------------------------------
__global__ __launch_bounds__(256) void tab_kernel(
    const float* __restrict__ q1, const float2* __restrict__ part1,
    const float* __restrict__ ln1w, const float* __restrict__ ln1b,
    f2* __restrict__ tab)
{
    int lane = threadIdx.x & 63;
    int bc   = blockIdx.x * 4 + (threadIdx.x >> 6);
    int b = bc / CC;
    int c = bc - b * CC;

    float s1 = 0.f, ss1 = 0.f;
    if (lane < MIDBLK) {
        float2 p = part1[b * MIDBLK + lane];
        s1 = p.x; ss1 = p.y;
    }
#pragma unroll
    for (int o = 32; o > 0; o >>= 1) {
        s1  += __shfl_down(s1, o, 64);
        ss1 += __shfl_down(ss1, o, 64);
    }
    s1  = __shfl(s1, 0, 64);
    ss1 = __shfl(ss1, 0, 64);
    float m = s1 * (1.f / CKK);
    float r = rsqrtf(ss1 * (1.f / CKK) - m * m + 1e-5f);

    float kt = 0.f;
    if (lane < KK) {
        float v = (q1[(size_t)bc * KK + lane] - m) * r * ln1w[c * KK + lane]
                  + ln1b[c * KK + lane];
        kt = v > 0.f ? v : 0.f;
    }

    int iA = 0, iB = 0;
    bool mA = false, mB = false;
    if (lane < 28) {
        int d = lane / KS, v = lane - KS * d;
        mA = (d < 3); iA = mA ? (2 * d + 1) * KS + v : 0;
        mB = (d > 0); iB = mB ? (2 * d - 1) * KS + v : 0;
    } else if (lane < 44) {
        int t = lane - 28;
        int d = t >> 2, j = t & 3;
        mA = true;     iA = 2 * d * KS + 2 * j;
        mB = (j < 3);  iB = mB ? 2 * d * KS + 2 * j + 1 : 0;
    }
    float va = __shfl(kt, iA, 64);
    float vb = __shfl(kt, iB, 64);
    f2 p;
    p.x = mA ? va : 0.f;
    p.y = mB ? vb : 0.f;

    f2* row = tab + (size_t)bc * 44;
    if (lane < 28)      row[16 + lane] = p;
    else if (lane < 44) row[lane - 28] = p;
}

// ---------------------------------------------------------------------------
// K4: per-(b,c) depthwise 7x7 SAME conv — TWO channels per block.
// 512 threads = 8 waves; waves 0-3 own channel 2*blk (tile 0), waves 4-7 own
// channel 2*blk+1 (tile 1). All 1024 stage loads issue before ONE barrier;
// per-channel prologue/barrier overhead halved; 4 blocks/CU x 8 waves = full
// occupancy. Main loop/staging/halo byte-identical to R13 (verified).
// ---------------------------------------------------------------------------
#define TW2 64

// acc.lo += vp.lo*tp.lo ; acc.hi += vp.hi*tp.lo   (diag, tap lo)
__device__ __forceinline__ void pkfma_dl(f2& acc, f2 vp, f2 tp) {
    asm("v_pk_fma_f32 %0, %1, %2, %0 op_sel_hi:[1,0,1]"
        : "+v"(acc) : "v"(vp), "s"(tp));
}
// acc.lo += vp.lo*tp.hi ; acc.hi += vp.hi*tp.hi   (diag, tap hi)
__device__ __forceinline__ void pkfma_dh(f2& acc, f2 vp, f2 tp) {
    asm("v_pk_fma_f32 %0, %1, %2, %0 op_sel:[0,1,0] op_sel_hi:[1,1,1]"
        : "+v"(acc) : "v"(vp), "s"(tp));
}
// acc.lo += vp.hi*tp.lo ; acc.hi += vp.lo*tp.hi   (cross, swapped rows)
__device__ __forceinline__ void pkfma_x(f2& acc, f2 vp, f2 tp) {
    asm("v_pk_fma_f32 %0, %1, %2, %0 op_sel:[1,0,0] op_sel_hi:[0,1,1]"
        : "+v"(acc) : "v"(vp), "s"(tp));
}

__global__ __launch_bounds__(512) void conv_kernel(
    const float* __restrict__ x,
    const f2* __restrict__ tab,
    float* __restrict__ out)
{
    __shared__ f2 tile2[2][32 * TW2];   // 32 KB; two channels
    int tid  = threadIdx.x;
    int lane = tid & 63;
    int wids = __builtin_amdgcn_readfirstlane(tid) >> 6;   // scalar wave id 0..7
    int half = wids >> 2;                                  // scalar: channel half
    int widL = wids & 3;                                   // scalar: strip id 0..3
    int bch  = blockIdx.x * 2 + half;                      // this wave's channel

    // ---- tap tables for this wave's channel -> SGPRs (scalar address) ----
    const float4* tb4 = (const float4*)(tab + (size_t)bch * 44);
    f2 dp[16], cpx[28];
#pragma unroll
    for (int i = 0; i < 8; ++i) {
        float4 t4 = tb4[i];
        dp[2 * i]     = (f2){t4.x, t4.y};
        dp[2 * i + 1] = (f2){t4.z, t4.w};
    }
#pragma unroll
    for (int i = 0; i < 14; ++i) {
        float4 t4 = tb4[8 + i];
        cpx[2 * i]     = (f2){t4.x, t4.y};
        cpx[2 * i + 1] = (f2){t4.z, t4.w};
    }

    // ---- issue global stage loads: each 256-thread half stages its channel ----
    const float* src = x + (size_t)bch * HW;
    f2* tile = tile2[half];
    int st = tid & 255;
    int t0 = st, t1 = st + 256;                   // tasks 0..405
    int pr2a = 1 + t0 / 14, qa = t0 - (pr2a - 1) * 14;
    int pr2b = 1 + t1 / 14, qb = t1 - (pr2b - 1) * 14;
    int rAa = 2 * pr2a - 3, rBa = rAa + 1;
    int rAb = 2 * pr2b - 3, rBb = rAb + 1;
    float4 z4 = make_float4(0.f, 0.f, 0.f, 0.f);
    float4 a0 = (rAa >= 0) ? *(const float4*)(src + rAa * WW + 4 * qa) : z4;
    float4 b0 = (rBa < HH) ? *(const float4*)(src + rBa * WW + 4 * qa) : z4;
    float4 a1 = z4, b1 = z4;
    if (t1 < 29 * 14) {
        a1 = *(const float4*)(src + rAb * WW + 4 * qb);            // rAb >= 33
        b1 = (rBb < HH) ? *(const float4*)(src + rBb * WW + 4 * qb) : z4;
    }

    // ---- halo-only zero on this half's tile (disjoint from staged cells) ----
    if (st < 128) {                        // rowpairs 0 and 30, full width
        int pr2 = (st < 64) ? 0 : 30;
        tile[pr2 * TW2 + (st & 63)] = (f2){0.f, 0.f};
    }
    if (st < 232) {                        // edge cols of rowpairs 1..29
        int pr2 = 1 + (st >> 3);
        int c8  = st & 7;
        int cell = (c8 < 3) ? c8 : 56 + c8;   // 0,1,2,59,60,61,62,63
        tile[pr2 * TW2 + cell] = (f2){0.f, 0.f};
    }

    // ---- staged writes (compiler inserts vmcnt waits) ----
    {
        f2* cell = tile + pr2a * TW2 + 3 + 4 * qa;
        cell[0] = (f2){a0.x, b0.x};
        cell[1] = (f2){a0.y, b0.y};
        cell[2] = (f2){a0.z, b0.z};
        cell[3] = (f2){a0.w, b0.w};
    }
    if (t1 < 29 * 14) {
        f2* cell = tile + pr2b * TW2 + 3 + 4 * qb;
        cell[0] = (f2){a1.x, b1.x};
        cell[1] = (f2){a1.y, b1.y};
        cell[2] = (f2){a1.z, b1.z};
        cell[3] = (f2){a1.w, b1.w};
    }
    __syncthreads();

    // ---- main loop: ping-pong prefetch, acc forwarding (R13-verified) ----
    int r0 = widL * 14;
    const f2* base = tile + (widL * 7) * TW2 + lane;
    f2 acc2[7];
#pragma unroll
    for (int t = 0; t < 7; ++t) acc2[t] = (f2){0.f, 0.f};

    f2 va[KS], vb[KS];
#pragma unroll
    for (int j = 0; j < KS; ++j) va[j] = base[j];          // rowpair s=0

#define CONV_STEP(S, CUR)                                              \
    {                                                                  \
        _Pragma("unroll")                                              \
        for (int d = 0; d < 4; ++d) {                                  \
            int t = (S) - d;                                           \
            if (t >= 0 && t <= 6) {                                    \
                _Pragma("unroll")                                      \
                for (int v = 0; v < KS; ++v) {                         \
                    if (v & 1) pkfma_dh(acc2[t], CUR[v], dp[d * 4 + (v >> 1)]); \
                    else       pkfma_dl(acc2[t], CUR[v], dp[d * 4 + (v >> 1)]); \
                    pkfma_x(acc2[t], CUR[v], cpx[d * KS + v]);         \
                }                                                      \
            }                                                          \
        }                                                              \
    }

#pragma unroll
    for (int ss = 0; ss < 5; ++ss) {
        int s0 = 2 * ss, s1 = 2 * ss + 1;
        {   // prefetch rowpair s1 into vb
            const f2* np = base + s1 * TW2;
#pragma unroll
            for (int j = 0; j < KS; ++j) vb[j] = np[j];
        }
        CONV_STEP(s0, va);
        if (ss < 4) {   // prefetch rowpair s0+2 into va
            const f2* np = base + (s0 + 2) * TW2;
#pragma unroll
            for (int j = 0; j < KS; ++j) va[j] = np[j];
        }
        CONV_STEP(s1, vb);
    }
#undef CONV_STEP

    if (lane < WW) {
        float* ob = out + (size_t)bch * HW + r0 * WW + lane;
#pragma unroll
        for (int t = 0; t < 7; ++t) {
            ob[(2 * t) * WW]     = acc2[t].x;
            ob[(2 * t + 1) * WW] = acc2[t].y;
        }
    }
}

// ---------------------------------------------------------------------------
extern "C" void kernel_launch(void* const* d_in, const int* in_sizes, int n_in,
                              void* d_out, int out_size, void* d_ws, size_t ws_size,
                              hipStream_t stream) {
    const float* x    = (const float*)d_in[0];
    const float* ln0w = (const float*)d_in[1];
    const float* ln0b = (const float*)d_in[2];
    const float* w0   = (const float*)d_in[3];
    const float* ln1w = (const float*)d_in[4];
    const float* ln1b = (const float*)d_in[5];
    float* out = (float*)d_out;

    float*  p0    = (float*)d_ws;                    // [NCELL]
    float*  q1    = p0 + NCELL;                      // [NCELL]
    float2* part0 = (float2*)(q1 + NCELL);           // [BB*P0BLK]
    float2* part1 = part0 + BB * P0BLK;              // [BB*MIDBLK]
    f2*     tab   = (f2*)(part1 + BB * MIDBLK);      // [NBC*44]

    pool_kernel<<<BB * P0BLK, 256, 0, stream>>>(x, p0, part0);
    mid_kernel <<<BB * MIDBLK, 512, 0, stream>>>(p0, ln0w, ln0b, w0, part0, q1, part1);
    tab_kernel <<<NBC / 4, 256, 0, stream>>>(q1, part1, ln1w, ln1b, tab);
    conv_kernel<<<NBC / 2, 512, 0, stream>>>(x, tab, out);
}

// Round 15
// 64.934 us; speedup vs baseline: 1.1042x; 1.0050x over previous
//
#include <hip/hip_runtime.h>

// Problem constants (B,C,H,W,K) = (32,192,56,56,7)
#define BB 32
#define CC 192
#define HH 56
#define WW 56
#define KS 7
#define HW 3136        // 56*56
#define KK 49
#define CKK 9408       // C*K*K
#define PL 8
#define NCELL (BB * CC * KK)   // 301056
#define NBC (BB * CC)          // 6144
#define P0BLK 37               // pool blocks per sample
#define MIDBLK 24              // mid blocks per sample

typedef float f2 __attribute__((ext_vector_type(2)));

// ---------------------------------------------------------------------------
// K1: avg pool 56x56 -> 7x7 + per-block LN0 partials (no atomics).
// ---------------------------------------------------------------------------
__global__ __launch_bounds__(256) void pool_kernel(const float* __restrict__ x,
                                                   float* __restrict__ p0,
                                                   float2* __restrict__ part0) {
    __shared__ float red[8];
    int b = blockIdx.x / P0BLK;
    int t = blockIdx.x - b * P0BLK;
    int cell = t * 256 + threadIdx.x;
    float v = 0.f;
    if (cell < CKK) {
        int c = cell / KK;
        int r = cell - c * KK;
        int i = r / KS;
        int j = r - i * KS;
        const float* src = x + ((size_t)(b * CC + c)) * HW + (i * PL) * WW + j * PL;
        float s = 0.f;
#pragma unroll
        for (int a = 0; a < PL; ++a) {
            float4 v0 = *(const float4*)(src + a * WW);
            float4 v1 = *(const float4*)(src + a * WW + 4);
            s += v0.x + v0.y + v0.z + v0.w + v1.x + v1.y + v1.z + v1.w;
        }
        v = s * (1.f / 64.f);
        p0[b * CKK + cell] = v;
    }
    float sv = v, sq = v * v;
#pragma unroll
    for (int o = 32; o > 0; o >>= 1) {
        sv += __shfl_down(sv, o, 64);
        sq += __shfl_down(sq, o, 64);
    }
    if ((threadIdx.x & 63) == 0) {
        red[(threadIdx.x >> 6) * 2 + 0] = sv;
        red[(threadIdx.x >> 6) * 2 + 1] = sq;
    }
    __syncthreads();
    if (threadIdx.x == 0)
        part0[blockIdx.x] = make_float2(red[0] + red[2] + red[4] + red[6],
                                        red[1] + red[3] + red[5] + red[7]);
}

// ---------------------------------------------------------------------------
// K2: LN0-normalize + depthwise 7x7 conv on the 7x7 map, one WAVE per (b,c).
// ---------------------------------------------------------------------------
__global__ __launch_bounds__(512) void mid_kernel(
    const float* __restrict__ p0,
    const float* __restrict__ ln0w, const float* __restrict__ ln0b,
    const float* __restrict__ w0,
    const float2* __restrict__ part0,
    float* __restrict__ q1,
    float2* __restrict__ part1)
{
    __shared__ float red[16];
    int tid  = threadIdx.x;
    int lane = tid & 63;
    int bc   = blockIdx.x * 8 + (tid >> 6);
    int b = bc / CC;
    int c = bc - b * CC;

    float s0 = 0.f, ss0 = 0.f;
    if (lane < P0BLK) {
        float2 p = part0[b * P0BLK + lane];
        s0 = p.x; ss0 = p.y;
    }
#pragma unroll
    for (int o = 32; o > 0; o >>= 1) {
        s0  += __shfl_down(s0, o, 64);
        ss0 += __shfl_down(ss0, o, 64);
    }
    s0  = __shfl(s0, 0, 64);
    ss0 = __shfl(ss0, 0, 64);
    float mean = s0 * (1.f / CKK);
    float rstd = rsqrtf(ss0 * (1.f / CKK) - mean * mean + 1e-5f);

    float val = 0.f;
    if (lane < KK)
        val = (p0[bc * KK + lane] - mean) * rstd * ln0w[c * KK + lane]
              + ln0b[c * KK + lane];

    int i0 = lane / KS;
    int j0 = lane - i0 * KS;
    const float* wc = w0 + c * KK;

    float acc = 0.f;
#pragma unroll
    for (int u = 0; u < KS; ++u) {
        int ii = i0 + u - 3;
#pragma unroll
        for (int v = 0; v < KS; ++v) {
            int jj = j0 + v - 3;
            bool ok = (ii >= 0) && (ii < KS) && (jj >= 0) && (jj < KS);
            int sl = ok ? (ii * KS + jj) : 0;
            float sv = __shfl(val, sl, 64);
            acc += ok ? sv * wc[u * KS + v] : 0.f;
        }
    }
    if (lane >= KK) acc = 0.f;
    if (lane < KK) q1[bc * KK + lane] = acc;

    float s2 = acc, ss2 = acc * acc;
#pragma unroll
    for (int o = 32; o > 0; o >>= 1) {
        s2  += __shfl_down(s2, o, 64);
        ss2 += __shfl_down(ss2, o, 64);
    }
    if (lane == 0) {
        red[(tid >> 6) * 2 + 0] = s2;
        red[(tid >> 6) * 2 + 1] = ss2;
    }
    __syncthreads();
    if (tid == 0) {
        float a = 0.f, q = 0.f;
#pragma unroll
        for (int w = 0; w < 8; ++w) { a += red[2 * w]; q += red[2 * w + 1]; }
        part1[blockIdx.x] = make_float2(a, q);
    }
}

// ---------------------------------------------------------------------------
// K3: tab_kernel — LN1+ReLU on q1 and dtab/ctab construction, one wave per bc.
// ---------------------------------------------------------------------------
__global__ __launch_bounds__(256) void tab_kernel(
    const float* __restrict__ q1, const float2* __restrict__ part1,
    const float* __restrict__ ln1w, const float* __restrict__ ln1b,
    f2* __restrict__ tab)
{
    int lane = threadIdx.x & 63;
    int bc   = blockIdx.x * 4 + (threadIdx.x >> 6);
    int b = bc / CC;
    int c = bc - b * CC;

    float s1 = 0.f, ss1 = 0.f;
    if (lane < MIDBLK) {
        float2 p = part1[b * MIDBLK + lane];
        s1 = p.x; ss1 = p.y;
    }
#pragma unroll
    for (int o = 32; o > 0; o >>= 1) {
        s1  += __shfl_down(s1, o, 64);
        ss1 += __shfl_down(ss1, o, 64);
    }
    s1  = __shfl(s1, 0, 64);
    ss1 = __shfl(ss1, 0, 64);
    float m = s1 * (1.f / CKK);
    float r = rsqrtf(ss1 * (1.f / CKK) - m * m + 1e-5f);

    float kt = 0.f;
    if (lane < KK) {
        float v = (q1[(size_t)bc * KK + lane] - m) * r * ln1w[c * KK + lane]
                  + ln1b[c * KK + lane];
        kt = v > 0.f ? v : 0.f;
    }

    int iA = 0, iB = 0;
    bool mA = false, mB = false;
    if (lane < 28) {
        int d = lane / KS, v = lane - KS * d;
        mA = (d < 3); iA = mA ? (2 * d + 1) * KS + v : 0;
        mB = (d > 0); iB = mB ? (2 * d - 1) * KS + v : 0;
    } else if (lane < 44) {
        int t = lane - 28;
        int d = t >> 2, j = t & 3;
        mA = true;     iA = 2 * d * KS + 2 * j;
        mB = (j < 3);  iB = mB ? 2 * d * KS + 2 * j + 1 : 0;
    }
    float va = __shfl(kt, iA, 64);
    float vb = __shfl(kt, iB, 64);
    f2 p;
    p.x = mA ? va : 0.f;
    p.y = mB ? vb : 0.f;

    f2* row = tab + (size_t)bc * 44;
    if (lane < 28)      row[16 + lane] = p;
    else if (lane < 44) row[lane - 28] = p;
}

// ---------------------------------------------------------------------------
// K4: per-(b,c) depthwise 7x7 SAME conv — sequential 2-channel double-buffer.
// Stage A -> bar -> ISSUE B's global loads -> compute A (hides B's HBM
// latency) -> write B to LDS -> bar -> compute B. Paired-b128 staging writes
// (column pad 4), halo zeros for both tiles upfront. Main loop = R13/R14-
// verified row-pair algebra (reads shifted +1 cell for pad-4).
// ---------------------------------------------------------------------------
#define TW2 64

// acc.lo += vp.lo*tp.lo ; acc.hi += vp.hi*tp.lo   (diag, tap lo)
__device__ __forceinline__ void pkfma_dl(f2& acc, f2 vp, f2 tp) {
    asm("v_pk_fma_f32 %0, %1, %2, %0 op_sel_hi:[1,0,1]"
        : "+v"(acc) : "v"(vp), "s"(tp));
}
// acc.lo += vp.lo*tp.hi ; acc.hi += vp.hi*tp.hi   (diag, tap hi)
__device__ __forceinline__ void pkfma_dh(f2& acc, f2 vp, f2 tp) {
    asm("v_pk_fma_f32 %0, %1, %2, %0 op_sel:[0,1,0] op_sel_hi:[1,1,1]"
        : "+v"(acc) : "v"(vp), "s"(tp));
}
// acc.lo += vp.hi*tp.lo ; acc.hi += vp.lo*tp.hi   (cross, swapped rows)
__device__ __forceinline__ void pkfma_x(f2& acc, f2 vp, f2 tp) {
    asm("v_pk_fma_f32 %0, %1, %2, %0 op_sel:[1,0,0] op_sel_hi:[0,1,1]"
        : "+v"(acc) : "v"(vp), "s"(tp));
}

struct Task { int pr2a, qa, pr2b, qb; bool has1; };

__device__ __forceinline__ Task task_decode(int tid) {
    Task t;
    int t0 = tid, t1 = tid + 256;
    t.pr2a = 1 + t0 / 14; t.qa = t0 - (t.pr2a - 1) * 14;
    t.pr2b = 1 + t1 / 14; t.qb = t1 - (t.pr2b - 1) * 14;
    t.has1 = (t1 < 29 * 14);
    return t;
}

__device__ __forceinline__ void stage_load(const float* __restrict__ src,
                                           const Task& tk, float4& a0, float4& b0,
                                           float4& a1, float4& b1) {
    float4 z4 = make_float4(0.f, 0.f, 0.f, 0.f);
    int rAa = 2 * tk.pr2a - 3, rBa = rAa + 1;
    a0 = (rAa >= 0) ? *(const float4*)(src + rAa * WW + 4 * tk.qa) : z4;
    b0 = (rBa < HH) ? *(const float4*)(src + rBa * WW + 4 * tk.qa) : z4;
    a1 = z4; b1 = z4;
    if (tk.has1) {
        int rAb = 2 * tk.pr2b - 3, rBb = rAb + 1;
        a1 = *(const float4*)(src + rAb * WW + 4 * tk.qb);          // rAb >= 33
        b1 = (rBb < HH) ? *(const float4*)(src + rBb * WW + 4 * tk.qb) : z4;
    }
}

__device__ __forceinline__ void stage_write(f2* tile, const Task& tk,
                                            const float4& a0, const float4& b0,
                                            const float4& a1, const float4& b1) {
    float4* c0 = (float4*)(tile + tk.pr2a * TW2 + 4 + 4 * tk.qa);   // even cell
    c0[0] = make_float4(a0.x, b0.x, a0.y, b0.y);
    c0[1] = make_float4(a0.z, b0.z, a0.w, b0.w);
    if (tk.has1) {
        float4* c1 = (float4*)(tile + tk.pr2b * TW2 + 4 + 4 * tk.qb);
        c1[0] = make_float4(a1.x, b1.x, a1.y, b1.y);
        c1[1] = make_float4(a1.z, b1.z, a1.w, b1.w);
    }
}

// zero halo of BOTH tiles: rows 0/30 full + edge cells 0-3,60-63 of rows 1-29
__device__ __forceinline__ void halo_zero(f2* t0, f2* t1, int tid) {
    for (int i = tid; i < 360; i += 256) {
        f2* tile = (i < 180) ? t0 : t1;
        int r = (i < 180) ? i : i - 180;
        int pr2, cell;
        if (r < 116) {
            pr2 = 1 + (r >> 2);
            int p = r & 3;
            cell = (p < 2) ? p * 2 : 60 + (p - 2) * 2;
        } else {
            int rr = r - 116;
            pr2 = (rr < 32) ? 0 : 30;
            cell = (rr & 31) * 2;
        }
        *(float4*)(tile + pr2 * TW2 + cell) = make_float4(0.f, 0.f, 0.f, 0.f);
    }
}

__device__ __forceinline__ void compute_store(const f2* tile,
                                              const f2* __restrict__ tabp,
                                              float* __restrict__ ob,
                                              int lane, int wid) {
    const float4* tb4 = (const float4*)tabp;
    f2 dp[16], cpx[28];
#pragma unroll
    for (int i = 0; i < 8; ++i) {
        float4 t4 = tb4[i];
        dp[2 * i]     = (f2){t4.x, t4.y};
        dp[2 * i + 1] = (f2){t4.z, t4.w};
    }
#pragma unroll
    for (int i = 0; i < 14; ++i) {
        float4 t4 = tb4[8 + i];
        cpx[2 * i]     = (f2){t4.x, t4.y};
        cpx[2 * i + 1] = (f2){t4.z, t4.w};
    }

    int r0 = wid * 14;
    const f2* base = tile + (wid * 7) * TW2 + lane + 1;   // pad-4: +1 cell
    f2 acc2[7];
#pragma unroll
    for (int t = 0; t < 7; ++t) acc2[t] = (f2){0.f, 0.f};

    f2 va[KS], vb[KS];
#pragma unroll
    for (int j = 0; j < KS; ++j) va[j] = base[j];          // rowpair s=0

#define CONV_STEP(S, CUR)                                              \
    {                                                                  \
        _Pragma("unroll")                                              \
        for (int d = 0; d < 4; ++d) {                                  \
            int t = (S) - d;                                           \
            if (t >= 0 && t <= 6) {                                    \
                _Pragma("unroll")                                      \
                for (int v = 0; v < KS; ++v) {                         \
                    if (v & 1) pkfma_dh(acc2[t], CUR[v], dp[d * 4 + (v >> 1)]); \
                    else       pkfma_dl(acc2[t], CUR[v], dp[d * 4 + (v >> 1)]); \
                    pkfma_x(acc2[t], CUR[v], cpx[d * KS + v]);         \
                }                                                      \
            }                                                          \
        }                                                              \
    }

#pragma unroll
    for (int ss = 0; ss < 5; ++ss) {
        int s0 = 2 * ss, s1 = 2 * ss + 1;
        {
            const f2* np = base + s1 * TW2;
#pragma unroll
            for (int j = 0; j < KS; ++j) vb[j] = np[j];
        }
        CONV_STEP(s0, va);
        if (ss < 4) {
            const f2* np = base + (s0 + 2) * TW2;
#pragma unroll
            for (int j = 0; j < KS; ++j) va[j] = np[j];
        }
        CONV_STEP(s1, vb);
    }
#undef CONV_STEP

    if (lane < WW) {
#pragma unroll
        for (int t = 0; t < 7; ++t) {
            ob[(r0 + 2 * t) * WW + lane]     = acc2[t].x;
            ob[(r0 + 2 * t + 1) * WW + lane] = acc2[t].y;
        }
    }
}

__global__ __launch_bounds__(256) void conv_kernel(
    const float* __restrict__ x,
    const f2* __restrict__ tab,
    float* __restrict__ out)
{
    __shared__ f2 tiles[2][32 * TW2];   // 32 KB
    int tid  = threadIdx.x;
    int lane = tid & 63;
    int wid  = tid >> 6;
    int chA  = blockIdx.x * 2;
    int chB  = chA + 1;

    Task tk = task_decode(tid);
    float4 a0, b0, a1, b1;

    // ---- stage channel A ----
    stage_load(x + (size_t)chA * HW, tk, a0, b0, a1, b1);
    halo_zero(tiles[0], tiles[1], tid);
    stage_write(tiles[0], tk, a0, b0, a1, b1);
    __syncthreads();

    // ---- issue channel B's global loads (hide under A's compute) ----
    stage_load(x + (size_t)chB * HW, tk, a0, b0, a1, b1);
    __builtin_amdgcn_sched_barrier(0);   // pin the prefetch before compute

    // ---- compute + store channel A ----
    compute_store(tiles[0], tab + (size_t)chA * 44, out + (size_t)chA * HW,
                  lane, wid);

    // ---- land channel B into LDS (vmcnt wait here), then compute ----
    stage_write(tiles[1], tk, a0, b0, a1, b1);
    __syncthreads();
    compute_store(tiles[1], tab + (size_t)chB * 44, out + (size_t)chB * HW,
                  lane, wid);
}

// ---------------------------------------------------------------------------
extern "C" void kernel_launch(void* const* d_in, const int* in_sizes, int n_in,
                              void* d_out, int out_size, void* d_ws, size_t ws_size,
                              hipStream_t stream) {
    const float* x    = (const float*)d_in[0];
    const float* ln0w = (const float*)d_in[1];
    const float* ln0b = (const float*)d_in[2];
    const float* w0   = (const float*)d_in[3];
    const float* ln1w = (const float*)d_in[4];
    const float* ln1b = (const float*)d_in[5];
    float* out = (float*)d_out;

    float*  p0    = (float*)d_ws;                    // [NCELL]
    float*  q1    = p0 + NCELL;                      // [NCELL]
    float2* part0 = (float2*)(q1 + NCELL);           // [BB*P0BLK]
    float2* part1 = part0 + BB * P0BLK;              // [BB*MIDBLK]
    f2*     tab   = (f2*)(part1 + BB * MIDBLK);      // [NBC*44]

    pool_kernel<<<BB * P0BLK, 256, 0, stream>>>(x, p0, part0);
    mid_kernel <<<BB * MIDBLK, 512, 0, stream>>>(p0, ln0w, ln0b, w0, part0, q1, part1);
    tab_kernel <<<NBC / 4, 256, 0, stream>>>(q1, part1, ln1w, ln1b, tab);
    conv_kernel<<<NBC / 2, 256, 0, stream>>>(x, tab, out);
}